// Round 10
// baseline (133.804 us; speedup 1.0000x reference)
//
#include <hip/hip_runtime.h>
#include <math.h>

#define NN 20000   // nodes
#define NE 40000   // edges
#define H 64
#define F_ATOM 62
#define F_BOND 6
#define NB 512     // graphs

typedef _Float16 f16x8 __attribute__((ext_vector_type(8)));
typedef float f32x16 __attribute__((ext_vector_type(16)));

__device__ __forceinline__ float selu_f(float x) {
    const float scale = 1.0507009873554805f;
    const float alpha = 1.6732632423543772f;
    return scale * (x > 0.0f ? x : alpha * (__expf(x) - 1.0f));
}

__device__ __forceinline__ f16x8 splat8h(_Float16 x) {
    union { _Float16 h[2]; unsigned u; } p;
    p.h[0] = x; p.h[1] = x;
    union { unsigned u[4]; f16x8 v; } r;
    r.u[0] = p.u; r.u[1] = p.u; r.u[2] = p.u; r.u[3] = p.u;
    return r.v;
}

// Fused prep, role by blockIdx (256 threads each)  — round-8 verbatim (PASSED):
// [0,625)      : mlp2[kkpair][e] = packed f16x2 {relu(ef@Wm+bm)[2p], [2p+1]} via LDS transpose
// [625,5625)   : h = pad(nf) f32 + h_h f16 mirror
// [5625,5753)  : ewb = f16(Ew) in B-fragment-linear order
// [5753,7003)  : zero msg; [7003,7035): zero gsum
__global__ void prep_kernel(const float* __restrict__ nf, const float* __restrict__ ef,
                            const float* __restrict__ Wm, const float* __restrict__ bm,
                            const float* __restrict__ Ew,
                            float* __restrict__ h, _Float16* __restrict__ h_h,
                            unsigned* __restrict__ mlp2, _Float16* __restrict__ ewb,
                            float* __restrict__ msg, float* __restrict__ gsum) {
    const int bid = blockIdx.x;
    const int t = threadIdx.x;
    if (bid < 625) {
        __shared__ float st[64][65];
        const int el = t & 63;
        const int ig = t >> 6;                 // wave id; i = ig*16+p wave-uniform
        const int e = bid * 64 + el;
        const float* efe = ef + e * F_BOND;
        const float e0 = efe[0], e1 = efe[1], e2 = efe[2];
        const float e3 = efe[3], e4 = efe[4], e5 = efe[5];
#pragma unroll
        for (int p = 0; p < 16; ++p) {
            const int i = ig * 16 + p;
            float s = bm[i];
            s = fmaf(e0, Wm[0 * H + i], s);
            s = fmaf(e1, Wm[1 * H + i], s);
            s = fmaf(e2, Wm[2 * H + i], s);
            s = fmaf(e3, Wm[3 * H + i], s);
            s = fmaf(e4, Wm[4 * H + i], s);
            s = fmaf(e5, Wm[5 * H + i], s);
            st[i][el] = fmaxf(s, 0.0f);
        }
        __syncthreads();
        const int p = t >> 3;                  // kk-pair 0..31
        const int ch = t & 7;                  // 8-edge chunk
#pragma unroll
        for (int j = 0; j < 8; ++j) {
            const int e_l = ch * 8 + j;
            union { unsigned u; _Float16 hh[2]; } pk;
            pk.hh[0] = (_Float16)st[2 * p][e_l];
            pk.hh[1] = (_Float16)st[2 * p + 1][e_l];
            mlp2[(size_t)p * NE + bid * 64 + e_l] = pk.u;
        }
    } else if (bid < 5625) {
        int idx = (bid - 625) * 256 + t;
        int n = idx >> 6, c = idx & 63;
        float v = (c < F_ATOM) ? nf[n * F_ATOM + c] : 0.0f;
        h[idx] = v;
        h_h[idx] = (_Float16)v;
    } else if (bid < 5753) {
        int tid = (bid - 5625) * 256 + t;      // 0..32767
        int l = tid & 63;
        int nt = (tid >> 6) & 1;
        int c = tid >> 7;                      // 0..255 = kk*4 + cq
        int kk = c >> 2;
        int jbase = (c & 3) * 16 + (l >> 5) * 8;
        int i = nt * 32 + (l & 31);
        const float* src = Ew + kk * 4096 + i * 64 + jbase;
        _Float16* dst = ewb + tid * 8;
#pragma unroll
        for (int u = 0; u < 8; ++u) dst[u] = (_Float16)src[u];
    } else if (bid < 7003) {
        int idx = (bid - 5753) * 256 + t;
        reinterpret_cast<float4*>(msg)[idx] = make_float4(0.f, 0.f, 0.f, 0.f);
    } else {
        int idx = (bid - 7003) * 256 + t;
        reinterpret_cast<float4*>(gsum)[idx] = make_float4(0.f, 0.f, 0.f, 0.f);
    }
}

// Edge message. Block = 128 thr = 2 waves = 2 K-groups; each wave owns M=64
// (two 32-edge M-tiles, 4 accs) so every staged B-fragment is read ONCE from
// LDS and feeds 2 MFMAs (halves LDS-read/MFMA vs round 9). Grid = 625 exact.
// Per kk-step: __syncthreads (drains prev DMA) -> stage next 8KB slice -> compute.
// K-partials merged in LDS (stage area reused); atomics once (~10 MB).
// A-build / B byte-layout / C/D row formula: round-8/9 verbatim (PASSED, 6.1e-5).
__global__ __launch_bounds__(128, 2) void edge_message_mfma(
    const _Float16* __restrict__ h_h, const unsigned* __restrict__ mlp2,
    const int* __restrict__ ed, const int* __restrict__ er,
    const _Float16* __restrict__ ewb, float* __restrict__ msg)
{
    __shared__ float4 smem4[2048];        // 32 KB: stage [2 kg][2 buf][8 KB]; merge reuses 16 KB
    __shared__ int edom_s[64];

    const int t = threadIdx.x;
    const int lane = t & 63;
    const int kg = t >> 6;                // K-group 0..1 (kk in [kg*32, kg*32+32))
    const int l31 = lane & 31;
    const int hf = lane >> 5;
    const int eb = blockIdx.x * 64;

    if (t < 64) edom_s[t] = ed[eb + t];

    const int eA = eb + l31;              // M-tile 0 row (exact: 625*64 == NE)
    const int eB = eA + 32;               // M-tile 1 row
    const int gA = er[eA], gB = er[eB];

    // hj fragments (f16): j = cq*16 + hf*8 + tt   (proven mapping)
    f16x8 hjA[4], hjB[4];
#pragma unroll
    for (int cq = 0; cq < 4; ++cq) {
        hjA[cq] = *reinterpret_cast<const f16x8*>(h_h + gA * 64 + cq * 16 + hf * 8);
        hjB[cq] = *reinterpret_cast<const f16x8*>(h_h + gB * 64 + cq * 16 + hf * 8);
    }

    // mlp pairs: kg covers pairs [kg*16, kg*16+16); pair pp -> kk {2pp, 2pp+1}
    unsigned mvA[16], mvB[16];
#pragma unroll
    for (int pp = 0; pp < 16; ++pp) {
        mvA[pp] = mlp2[(size_t)(kg * 16 + pp) * NE + eA];
        mvB[pp] = mlp2[(size_t)(kg * 16 + pp) * NE + eB];
    }

    char* sm = reinterpret_cast<char*>(smem4);
    // stage 8KB slice kk = kg*32+s into buf (kg*2 + (s&1)); whole wave stages it
    auto stage = [&](int s) {
        const char* gs = reinterpret_cast<const char*>(ewb) +
                         ((size_t)(kg * 32 + s) << 13) + lane * 16;
        char* lb = sm + ((size_t)(kg * 2 + (s & 1)) << 13) + lane * 16;
#pragma unroll
        for (int r = 0; r < 8; ++r) {
            __builtin_amdgcn_global_load_lds(
                (const __attribute__((address_space(1))) void*)(gs + r * 1024),
                (__attribute__((address_space(3))) void*)(lb + r * 1024),
                16, 0, 0);
        }
    };

    f32x16 a00, a01, a10, a11;
#pragma unroll
    for (int i = 0; i < 16; ++i) { a00[i] = 0.f; a01[i] = 0.f; a10[i] = 0.f; a11[i] = 0.f; }

    stage(0);

#pragma unroll
    for (int s = 0; s < 32; ++s) {
        __syncthreads();                  // stage(s) DMA drained (own vmcnt) + barrier
        if (s < 31) stage(s + 1);         // lands during compute(s)
        const char* buf = sm + ((size_t)(kg * 2 + (s & 1)) << 13);
        union { unsigned u; _Float16 hh[2]; } ua, ub;
        ua.u = mvA[s >> 1]; ub.u = mvB[s >> 1];
        f16x8 sA = splat8h(ua.hh[s & 1]);
        f16x8 sB = splat8h(ub.hh[s & 1]);
#pragma unroll
        for (int cq = 0; cq < 4; ++cq) {
            f16x8 b0 = *reinterpret_cast<const f16x8*>(buf + (cq * 2 + 0) * 1024 + lane * 16);
            f16x8 b1 = *reinterpret_cast<const f16x8*>(buf + (cq * 2 + 1) * 1024 + lane * 16);
            f16x8 aA = sA * hjA[cq];
            f16x8 aB = sB * hjB[cq];
            a00 = __builtin_amdgcn_mfma_f32_32x32x16_f16(aA, b0, a00, 0, 0, 0);
            a01 = __builtin_amdgcn_mfma_f32_32x32x16_f16(aA, b1, a01, 0, 0, 0);
            a10 = __builtin_amdgcn_mfma_f32_32x32x16_f16(aB, b0, a10, 0, 0, 0);
            a11 = __builtin_amdgcn_mfma_f32_32x32x16_f16(aB, b1, a11, 0, 0, 0);
        }
    }

    // ---- K-partial merge in LDS (stage area now dead) ----
    // C/D row formula (proven): m = (r&3) + 8*(r>>2) + 4*hf
    float* X = reinterpret_cast<float*>(smem4);        // 16 KB: [64 e_loc][64 col]
    __syncthreads();                      // all reads of stage LDS complete
    if (kg == 1) {
#pragma unroll
        for (int r = 0; r < 16; ++r) {
            const int m = (r & 3) + 8 * (r >> 2) + 4 * hf;
            X[m * 64 + l31]             = a00[r];
            X[m * 64 + 32 + l31]        = a01[r];
            X[(32 + m) * 64 + l31]      = a10[r];
            X[(32 + m) * 64 + 32 + l31] = a11[r];
        }
    }
    __syncthreads();
    if (kg == 0) {
#pragma unroll
        for (int r = 0; r < 16; ++r) {
            const int m = (r & 3) + 8 * (r >> 2) + 4 * hf;
            const int domA = edom_s[m];
            const int domB = edom_s[32 + m];
            atomicAdd(&msg[domA * 64 + l31],      a00[r] + X[m * 64 + l31]);
            atomicAdd(&msg[domA * 64 + 32 + l31], a01[r] + X[m * 64 + 32 + l31]);
            atomicAdd(&msg[domB * 64 + l31],      a10[r] + X[(32 + m) * 64 + l31]);
            atomicAdd(&msg[domB * 64 + 32 + l31], a11[r] + X[(32 + m) * 64 + 32 + l31]);
        }
    }
}

// h[n,i] = selu(msg[n] @ Wu + bu[i] + h[n,i]); h_h mirror; zeroes msg (round-8 verbatim)
__global__ void node_update_kernel(float* __restrict__ msg, const float* __restrict__ Wu,
                                   const float* __restrict__ bu, float* __restrict__ h,
                                   _Float16* __restrict__ h_h) {
    __shared__ float ms[4][68];
    int t = threadIdx.x;
    int nb = blockIdx.x * 4;
    int ln = t >> 6, i = t & 63;
    int o = (nb + ln) * H + i;
    ms[ln][i] = msg[o];
    msg[o] = 0.0f;                       // ready for next edge_message / replay
    __syncthreads();
    float s = bu[i];
#pragma unroll
    for (int k = 0; k < H; ++k) s = fmaf(ms[ln][k], Wu[k * H + i], s);
    float v = selu_f(s + h[o]);
    h[o] = v;
    h_h[o] = (_Float16)v;
}

// fused: ae = h@Wae+bae; aa = selu(ae@WR+bR); atomicAdd gsum[gid[n]]   (round-8 verbatim)
__global__ void embed_readout_kernel(const float* __restrict__ h, const float* __restrict__ Wae,
                                     const float* __restrict__ bae, const float* __restrict__ WR,
                                     const float* __restrict__ bR, const int* __restrict__ gid,
                                     float* __restrict__ gsum) {
    __shared__ float hs[4][68];
    __shared__ float as_[4][68];
    int t = threadIdx.x;
    int nb = blockIdx.x * 4;
    int ln = t >> 6, i = t & 63;
    hs[ln][i] = h[(nb + ln) * H + i];
    __syncthreads();
    float s = bae[i];
#pragma unroll
    for (int k = 0; k < H; ++k) s = fmaf(hs[ln][k], Wae[k * H + i], s);
    as_[ln][i] = s;
    __syncthreads();
    float s2 = bR[i];
#pragma unroll
    for (int k = 0; k < H; ++k) s2 = fmaf(as_[ln][k], WR[k * H + i], s2);
    atomicAdd(&gsum[gid[nb + ln] * H + i], selu_f(s2));
}

// per graph: ge = tanh(gsum); mo = relu(ge @ Wmlp + bmlp); out = mo @ Wout + bout (round-8 verbatim)
__global__ void final_kernel(const float* __restrict__ gsum, const float* __restrict__ Wmlp,
                             const float* __restrict__ bmlp, const float* __restrict__ Wout,
                             const float* __restrict__ bout, float* __restrict__ out) {
    __shared__ float ge[64];
    int g = blockIdx.x, i = threadIdx.x;
    ge[i] = tanhf(gsum[g * H + i]);
    __syncthreads();
    float s = bmlp[i];
#pragma unroll
    for (int k = 0; k < H; ++k) s = fmaf(ge[k], Wmlp[k * H + i], s);
    float mo = fmaxf(s, 0.0f) * Wout[i];
#pragma unroll
    for (int off = 32; off > 0; off >>= 1) mo += __shfl_down(mo, off);
    if (i == 0) out[g] = mo + bout[0];
}

extern "C" void kernel_launch(void* const* d_in, const int* in_sizes, int n_in,
                              void* d_out, int out_size, void* d_ws, size_t ws_size,
                              hipStream_t stream) {
    const float* nf   = (const float*)d_in[0];
    const float* ef   = (const float*)d_in[1];
    const int*   ed   = (const int*)d_in[2];   // edge_domain (scatter dest)
    const int*   er   = (const int*)d_in[3];   // edge_range  (gather src)
    const int*   gid  = (const int*)d_in[4];
    const float* Wm   = (const float*)d_in[5];
    const float* bm   = (const float*)d_in[6];
    const float* Ew   = (const float*)d_in[7];
    const float* Wu0  = (const float*)d_in[8];
    const float* bu0  = (const float*)d_in[9];
    const float* Wu1  = (const float*)d_in[10];
    const float* bu1  = (const float*)d_in[11];
    const float* Wae  = (const float*)d_in[12];
    const float* bae  = (const float*)d_in[13];
    const float* WR   = (const float*)d_in[14];
    const float* bR   = (const float*)d_in[15];
    const float* Wmlp = (const float*)d_in[16];
    const float* bmlp = (const float*)d_in[17];
    const float* Wout = (const float*)d_in[18];
    const float* bout = (const float*)d_in[19];
    float* out = (float*)d_out;

    float* ws = (float*)d_ws;
    float*    h    = ws;                              // 1,280,000 f32
    float*    msg  = ws + 1280000;                    // 1,280,000 f32
    float*    gsum = ws + 2560000;                    // 32,768 f32
    unsigned* mlp2 = (unsigned*)(ws + 2592768);       // 32*40000 u32 (f16x2 pairs)
    _Float16* h_h  = (_Float16*)(ws + 3872768);       // 1,280,000 f16
    _Float16* ewb  = (_Float16*)(ws + 4512768);       // 262,144 f16

    prep_kernel<<<7035, 256, 0, stream>>>(nf, ef, Wm, bm, Ew, h, h_h, mlp2, ewb, msg, gsum);

    for (int stepi = 0; stepi < 2; ++stepi) {
        edge_message_mfma<<<625, 128, 0, stream>>>(h_h, mlp2, ed, er, ewb, msg);
        node_update_kernel<<<NN / 4, 256, 0, stream>>>(msg, stepi ? Wu1 : Wu0,
                                                       stepi ? bu1 : bu0, h, h_h);
    }

    embed_readout_kernel<<<NN / 4, 256, 0, stream>>>(h, Wae, bae, WR, bR, gid, gsum);
    final_kernel<<<NB, 64, 0, stream>>>(gsum, Wmlp, bmlp, Wout, bout, out);
}